// Round 8
// baseline (1153.591 us; speedup 1.0000x reference)
//
#include <hip/hip_runtime.h>
#include <hip/hip_bf16.h>

// MoE conditional FFN: out[t,a] = (silu(w1[e]@x[t]) * (w3[e]@x[t])) @ w2[e]^T,
// e = expert_indices[t,a].  T=2048 A=2 E=8 D=2048 INTER=4096.
// Plan: route -> gather x (bf16) -> grouped GEMM1 (dual w1/w3, silu*mul, bf16 h)
//       -> grouped GEMM2 (h @ w2^T, scatter f32 to out).
// Weights stay f32 in HBM (read once: 805MB); converted to bf16 during LDS staging.

#define T_TOK 2048
#define A_ACT 2
#define E_EXP 8
#define D_DIM 2048
#define I_DIM 4096
#define TA    (T_TOK * A_ACT)   // 4096 (t,a) slots total
#define BK    32                // K-step (one 16x16x32 MFMA deep)

typedef __attribute__((ext_vector_type(4))) float f32x4;
typedef __attribute__((ext_vector_type(8))) short bf16x8;

static __device__ __forceinline__ short f2bf(float f) {
  union { __hip_bfloat16 b; short s; } u;
  u.b = __float2bfloat16(f);   // RNE
  return u.s;
}

static __device__ __forceinline__ void gload_lds16(const void* g, void* l) {
  // async global->LDS, 16B per lane; LDS dest is wave-uniform base + lane*16
  __builtin_amdgcn_global_load_lds(
      (const __attribute__((address_space(1))) unsigned int*)g,
      (__attribute__((address_space(3))) unsigned int*)l, 16, 0, 0);
}

// ---------------- routing: counts -> offsets -> perm (grouped by expert) ---------
__global__ void route_kernel(const int* __restrict__ idx, int* __restrict__ off,
                             int* __restrict__ perm) {
  __shared__ int scnt[E_EXP];
  __shared__ int scur[E_EXP];
  __shared__ int soff[E_EXP + 1];
  const int t = threadIdx.x;   // 1024 threads
  if (t < E_EXP) scnt[t] = 0;
  __syncthreads();
  for (int i = t; i < TA; i += 1024) atomicAdd(&scnt[idx[i]], 1);
  __syncthreads();
  if (t == 0) {
    int s = 0;
    for (int e = 0; e < E_EXP; ++e) { soff[e] = s; s += scnt[e]; }
    soff[E_EXP] = s;           // == TA always
  }
  __syncthreads();
  if (t < E_EXP) scur[t] = soff[t];
  if (t <= E_EXP) off[t] = soff[t];
  __syncthreads();
  for (int i = t; i < TA; i += 1024) {
    int e = idx[i];
    int p = atomicAdd(&scur[e], 1);
    perm[p] = i;               // i = t*A + a  == flat out-row index
  }
}

// ---------------- gather x rows (f32 -> bf16), one row per block ----------------
__global__ void gather_x(const float* __restrict__ x, const int* __restrict__ perm,
                         short* __restrict__ xg) {
  const int r = blockIdx.x;                 // 0..TA-1 (all slots valid)
  const int tok = perm[r] / A_ACT;
  const f32x4* src = (const f32x4*)(x + (size_t)tok * D_DIM);
  const int c = threadIdx.x;                // 256 threads * 8 elems = 2048
  f32x4 v0 = src[c * 2 + 0];
  f32x4 v1 = src[c * 2 + 1];
  bf16x8 o;
#pragma unroll
  for (int j = 0; j < 4; ++j) { o[j] = f2bf(v0[j]); o[4 + j] = f2bf(v1[j]); }
  *(bf16x8*)(xg + (size_t)r * D_DIM + c * 8) = o;
}

// LDS tiles are [rows][32] bf16 (64B rows, 4 x 16B chunks).  XOR chunk-swizzle:
// phys_chunk = logical_chunk ^ ((row>>1)&3)  -> ds_read_b128 spreads 16 lanes
// over 8 distinct 4-bank groups (2-way aliasing = free).  Staged both-sides:
// the global SOURCE chunk is inverse-swizzled, reads apply the same XOR.

// ---------------- GEMM1: h = silu(xg@w1^T) * (xg@w3^T), bf16 out ----------------
// block tile: 1024 tokens x 32 inter, 8 waves (each: 128 tokens x 32 inter)
__global__ __launch_bounds__(512, 2)
void gemm1_w13(const short* __restrict__ xg, const float* __restrict__ w1,
               const float* __restrict__ w3, const int* __restrict__ off,
               short* __restrict__ h) {
  const int e = blockIdx.z;
  const int off_e = off[e];
  const int cnt = off[e + 1] - off_e;
  const int n0 = blockIdx.y * 1024;         // token-tile base (within expert)
  if (n0 >= cnt) return;                    // uniform early-exit (before barriers)
  const int m0 = blockIdx.x * 32;           // inter base

  __shared__ __align__(16) short sA[2][1024 * BK];   // 2 x 64KB tokens
  __shared__ __align__(16) short sB1[2][32 * BK];    // w1 tile (bf16)
  __shared__ __align__(16) short sB3[2][32 * BK];    // w3 tile

  const int tid = threadIdx.x;
  const int w = tid >> 6;                   // wave 0..7 -> token rows [w*128, w*128+128)
  const int lane = tid & 63;
  const int lr = lane & 15;
  const int kq = lane >> 4;                 // k-quarter (8 bf16 each)
  const int pq = kq ^ ((lr >> 1) & 3);      // swizzled chunk for frag reads
  const bool wactive = (w * 128 < cnt - n0);  // skip MFMA on fully-padded waves

  // A staging: wave w stages exactly its own rows; 8 x 1KB segments
  const short* gA[8];
#pragma unroll
  for (int j = 0; j < 8; ++j) {
    int seg = (w * 8 + j) * 64 + lane;
    int row = seg >> 2;
    int qp = seg & 3;
    int ql = qp ^ ((row >> 1) & 3);         // inverse-swizzled source chunk
    int trow = n0 + row; if (trow > cnt - 1) trow = cnt - 1;   // clamp pad rows
    gA[j] = xg + (size_t)(off_e + trow) * D_DIM + ql * 8;
  }
  // B staging: threads 0..127 -> w1, 128..255 -> w3; 8 f32 -> 8 bf16 each
  const bool bstage = (tid < 256);
  const int bts = tid & 127;
  const int bwr = bts >> 2;                 // row 0..31 (inter)
  const int bqp = bts & 3;                  // physical chunk
  const float* gB;
  {
    int ql = bqp ^ ((bwr >> 1) & 3);
    const float* wsel = (tid < 128) ? w1 : w3;
    gB = wsel + (size_t)e * I_DIM * D_DIM + (size_t)(m0 + bwr) * D_DIM + ql * 8;
  }

  f32x4 acc1[8][2], acc3[8][2];
#pragma unroll
  for (int mi = 0; mi < 8; ++mi)
#pragma unroll
    for (int ni = 0; ni < 2; ++ni) {
      acc1[mi][ni] = (f32x4){0.f, 0.f, 0.f, 0.f};
      acc3[mi][ni] = (f32x4){0.f, 0.f, 0.f, 0.f};
    }

  auto stageA = [&](int nb, int k0) {
#pragma unroll
    for (int j = 0; j < 8; ++j)
      gload_lds16(gA[j] + k0, &sA[nb][(w * 8 + j) * 512]);
  };
  auto loadB = [&](int k0, f32x4& ra, f32x4& rb) {
    if (bstage) {
      const float* p = gB + k0;
      ra = *(const f32x4*)p;
      rb = *(const f32x4*)(p + 4);
    }
  };
  auto writeB = [&](int nb, const f32x4& ra, const f32x4& rb) {
    if (bstage) {
      bf16x8 o;
#pragma unroll
      for (int j = 0; j < 4; ++j) { o[j] = f2bf(ra[j]); o[4 + j] = f2bf(rb[j]); }
      short* dst = ((tid < 128) ? sB1[nb] : sB3[nb]) + bwr * BK + bqp * 8;
      *(bf16x8*)dst = o;
    }
  };

  const int NSTEP = D_DIM / BK;   // 64
  {
    f32x4 ra, rb;
    if (wactive) stageA(0, 0);
    loadB(0, ra, rb);
    writeB(0, ra, rb);
    __syncthreads();
  }
  for (int t = 0; t < NSTEP; ++t) {
    const int nb = t & 1, pf = nb ^ 1;
    const bool pfv = (t + 1 < NSTEP);
    f32x4 ra, rb;
    if (pfv) {
      if (wactive) stageA(pf, (t + 1) * BK);
      loadB((t + 1) * BK, ra, rb);
    }
    if (wactive) {
      const short* Ab = sA[nb] + ((w * 128 + lr) * BK + pq * 8);
      bf16x8 af[8];
#pragma unroll
      for (int mi = 0; mi < 8; ++mi)
        af[mi] = *(const bf16x8*)(Ab + mi * 16 * BK);
#pragma unroll
      for (int ni = 0; ni < 2; ++ni) {
        const int brow = ni * 16 + lr;
        bf16x8 b1 = *(const bf16x8*)(sB1[nb] + brow * BK + pq * 8);
        bf16x8 b3 = *(const bf16x8*)(sB3[nb] + brow * BK + pq * 8);
#pragma unroll
        for (int mi = 0; mi < 8; ++mi) {
          acc1[mi][ni] = __builtin_amdgcn_mfma_f32_16x16x32_bf16(af[mi], b1, acc1[mi][ni], 0, 0, 0);
          acc3[mi][ni] = __builtin_amdgcn_mfma_f32_16x16x32_bf16(af[mi], b3, acc3[mi][ni], 0, 0, 0);
        }
      }
    }
    if (pfv) writeB(pf, ra, rb);
    __syncthreads();
  }

  if (wactive) {
#pragma unroll
    for (int mi = 0; mi < 8; ++mi)
#pragma unroll
      for (int ni = 0; ni < 2; ++ni)
#pragma unroll
        for (int j = 0; j < 4; ++j) {
          int row = w * 128 + mi * 16 + kq * 4 + j;   // C/D: col=lane&15, row=(lane>>4)*4+j
          if (n0 + row < cnt) {
            int col = m0 + ni * 16 + lr;
            float z1 = acc1[mi][ni][j];
            float z3 = acc3[mi][ni][j];
            float sv = z1 / (1.0f + __expf(-z1));     // silu
            h[(size_t)(off_e + n0 + row) * I_DIM + col] = f2bf(sv * z3);
          }
        }
  }
}

// ---------------- GEMM2: out[perm] = h @ w2^T (f32 scatter) ---------------------
// block tile: 1024 tokens x 64 d, 8 waves (each: 128 tokens x 64 d)
__global__ __launch_bounds__(512, 2)
void gemm2_out(const short* __restrict__ h, const float* __restrict__ w2,
               const int* __restrict__ off, const int* __restrict__ perm,
               float* __restrict__ out) {
  const int e = blockIdx.z;
  const int off_e = off[e];
  const int cnt = off[e + 1] - off_e;
  const int n0 = blockIdx.y * 1024;
  if (n0 >= cnt) return;
  const int d0 = blockIdx.x * 64;

  __shared__ __align__(16) short sA[2][1024 * BK];   // h tokens
  __shared__ __align__(16) short sB[2][64 * BK];     // w2 tile (bf16)

  const int tid = threadIdx.x;
  const int w = tid >> 6;
  const int lane = tid & 63;
  const int lr = lane & 15;
  const int kq = lane >> 4;
  const int pq = kq ^ ((lr >> 1) & 3);
  const bool wactive = (w * 128 < cnt - n0);

  const short* gA[8];
#pragma unroll
  for (int j = 0; j < 8; ++j) {
    int seg = (w * 8 + j) * 64 + lane;
    int row = seg >> 2;
    int qp = seg & 3;
    int ql = qp ^ ((row >> 1) & 3);
    int trow = n0 + row; if (trow > cnt - 1) trow = cnt - 1;
    gA[j] = h + (size_t)(off_e + trow) * I_DIM + ql * 8;
  }
  const bool bstage = (tid < 256);
  const int bwr = (tid & 255) >> 2;          // row 0..63 (d)
  const int bqp = tid & 3;
  const float* gB;
  {
    int ql = bqp ^ ((bwr >> 1) & 3);
    gB = w2 + (size_t)e * D_DIM * I_DIM + (size_t)(d0 + bwr) * I_DIM + ql * 8;
  }

  f32x4 acc[8][4];
#pragma unroll
  for (int mi = 0; mi < 8; ++mi)
#pragma unroll
    for (int ni = 0; ni < 4; ++ni) acc[mi][ni] = (f32x4){0.f, 0.f, 0.f, 0.f};

  auto stageA = [&](int nb, int k0) {
#pragma unroll
    for (int j = 0; j < 8; ++j)
      gload_lds16(gA[j] + k0, &sA[nb][(w * 8 + j) * 512]);
  };
  auto loadB = [&](int k0, f32x4& ra, f32x4& rb) {
    if (bstage) {
      const float* p = gB + k0;
      ra = *(const f32x4*)p;
      rb = *(const f32x4*)(p + 4);
    }
  };
  auto writeB = [&](int nb, const f32x4& ra, const f32x4& rb) {
    if (bstage) {
      bf16x8 o;
#pragma unroll
      for (int j = 0; j < 4; ++j) { o[j] = f2bf(ra[j]); o[4 + j] = f2bf(rb[j]); }
      *(bf16x8*)(sB[nb] + bwr * BK + bqp * 8) = o;
    }
  };

  const int NSTEP = I_DIM / BK;   // 128
  {
    f32x4 ra, rb;
    if (wactive) stageA(0, 0);
    loadB(0, ra, rb);
    writeB(0, ra, rb);
    __syncthreads();
  }
  for (int t = 0; t < NSTEP; ++t) {
    const int nb = t & 1, pf = nb ^ 1;
    const bool pfv = (t + 1 < NSTEP);
    f32x4 ra, rb;
    if (pfv) {
      if (wactive) stageA(pf, (t + 1) * BK);
      loadB((t + 1) * BK, ra, rb);
    }
    if (wactive) {
      const short* Ab = sA[nb] + ((w * 128 + lr) * BK + pq * 8);
      bf16x8 af[8];
#pragma unroll
      for (int mi = 0; mi < 8; ++mi)
        af[mi] = *(const bf16x8*)(Ab + mi * 16 * BK);
#pragma unroll
      for (int ni = 0; ni < 4; ++ni) {
        bf16x8 b = *(const bf16x8*)(sB[nb] + (ni * 16 + lr) * BK + pq * 8);
#pragma unroll
        for (int mi = 0; mi < 8; ++mi)
          acc[mi][ni] = __builtin_amdgcn_mfma_f32_16x16x32_bf16(af[mi], b, acc[mi][ni], 0, 0, 0);
      }
    }
    if (pfv) writeB(pf, ra, rb);
    __syncthreads();
  }

  if (wactive) {
#pragma unroll
    for (int mi = 0; mi < 8; ++mi)
#pragma unroll
      for (int j = 0; j < 4; ++j) {
        int row = w * 128 + mi * 16 + kq * 4 + j;
        if (n0 + row < cnt) {
          int oi = perm[off_e + n0 + row];   // = t*A + a
#pragma unroll
          for (int ni = 0; ni < 4; ++ni)
            out[(size_t)oi * D_DIM + d0 + ni * 16 + lr] = acc[mi][ni][j];
        }
      }
  }
}

// ---------------- launch ---------------------------------------------------------
extern "C" void kernel_launch(void* const* d_in, const int* in_sizes, int n_in,
                              void* d_out, int out_size, void* d_ws, size_t ws_size,
                              hipStream_t stream) {
  const float* x  = (const float*)d_in[0];
  const int* idx  = (const int*)d_in[1];
  const float* w1 = (const float*)d_in[2];
  const float* w2 = (const float*)d_in[3];
  const float* w3 = (const float*)d_in[4];
  float* out = (float*)d_out;

  // workspace layout (needs ~50.4MB)
  int* off  = (int*)d_ws;                                  // 16 ints
  int* perm = off + 16;                                    // 4096 ints
  short* xg = (short*)((char*)d_ws + 32768);               // 4096x2048 bf16 = 16MB
  short* h  = (short*)((char*)d_ws + 32768 + (size_t)16 * 1024 * 1024);  // 4096x4096 bf16 = 32MB

  route_kernel<<<1, 1024, 0, stream>>>(idx, off, perm);
  gather_x<<<TA, 256, 0, stream>>>(x, perm, xg);
  gemm1_w13<<<dim3(I_DIM / 32, TA / 1024, E_EXP), 512, 0, stream>>>(xg, w1, w3, off, h);
  gemm2_out<<<dim3(D_DIM / 64, TA / 1024, E_EXP), 512, 0, stream>>>(h, w2, off, perm, out);
}

// Round 9
// 1000.908 us; speedup vs baseline: 1.1525x; 1.1525x over previous
//
#include <hip/hip_runtime.h>
#include <hip/hip_bf16.h>

// MoE conditional FFN: out[t,a] = (silu(w1[e]@x[t]) * (w3[e]@x[t])) @ w2[e]^T.
// R8 profile: 1 block/CU (136KB LDS), 2 waves/SIMD -> latency-bound (Mfma 14%,
// VALU 10%, HBM 10%, Occ 23%).  R9: 256x64 tiles, 48KB LDS, launch_bounds(512,4)
// -> 2 blocks/CU, 4 waves/SIMD, inter-block overlap hides the barrier drain.

#define T_TOK 2048
#define A_ACT 2
#define E_EXP 8
#define D_DIM 2048
#define I_DIM 4096
#define TA    (T_TOK * A_ACT)
#define BK    32

typedef __attribute__((ext_vector_type(4))) float f32x4;
typedef __attribute__((ext_vector_type(8))) short bf16x8;

static __device__ __forceinline__ short f2bf(float f) {
  union { __hip_bfloat16 b; short s; } u;
  u.b = __float2bfloat16(f);
  return u.s;
}

static __device__ __forceinline__ void gload_lds16(const void* g, void* l) {
  __builtin_amdgcn_global_load_lds(
      (const __attribute__((address_space(1))) unsigned int*)g,
      (__attribute__((address_space(3))) unsigned int*)l, 16, 0, 0);
}

// ---------------- routing ---------------------------------------------------
__global__ void route_kernel(const int* __restrict__ idx, int* __restrict__ off,
                             int* __restrict__ perm) {
  __shared__ int scnt[E_EXP];
  __shared__ int scur[E_EXP];
  __shared__ int soff[E_EXP + 1];
  const int t = threadIdx.x;
  if (t < E_EXP) scnt[t] = 0;
  __syncthreads();
  for (int i = t; i < TA; i += 1024) atomicAdd(&scnt[idx[i]], 1);
  __syncthreads();
  if (t == 0) {
    int s = 0;
    for (int e = 0; e < E_EXP; ++e) { soff[e] = s; s += scnt[e]; }
    soff[E_EXP] = s;
  }
  __syncthreads();
  if (t < E_EXP) scur[t] = soff[t];
  if (t <= E_EXP) off[t] = soff[t];
  __syncthreads();
  for (int i = t; i < TA; i += 1024) {
    int e = idx[i];
    int p = atomicAdd(&scur[e], 1);
    perm[p] = i;
  }
}

// ---------------- gather x rows (f32 -> bf16) --------------------------------
__global__ void gather_x(const float* __restrict__ x, const int* __restrict__ perm,
                         short* __restrict__ xg) {
  const int r = blockIdx.x;
  const int tok = perm[r] / A_ACT;
  const f32x4* src = (const f32x4*)(x + (size_t)tok * D_DIM);
  const int c = threadIdx.x;
  f32x4 v0 = src[c * 2 + 0];
  f32x4 v1 = src[c * 2 + 1];
  bf16x8 o;
#pragma unroll
  for (int j = 0; j < 4; ++j) { o[j] = f2bf(v0[j]); o[4 + j] = f2bf(v1[j]); }
  *(bf16x8*)(xg + (size_t)r * D_DIM + c * 8) = o;
}

// LDS tiles [rows][32] bf16; chunk-XOR swizzle phys = logical ^ ((row>>1)&3),
// applied on BOTH sides (inverse-swizzled global source, swizzled read).

// ---------------- GEMM1: 256 tok x 64 inter, 8 waves (64x32 each) ------------
__global__ __launch_bounds__(512, 4)
void gemm1_w13(const short* __restrict__ xg, const float* __restrict__ w1,
               const float* __restrict__ w3, const int* __restrict__ off,
               short* __restrict__ h) {
  const int e = blockIdx.z;
  const int off_e = off[e];
  const int cnt = off[e + 1] - off_e;
  const int n0 = blockIdx.y * 256;
  if (n0 >= cnt) return;
  const int m0 = blockIdx.x * 64;

  __shared__ __align__(16) short sA[2][256 * BK];   // 32 KB
  __shared__ __align__(16) short sB1[2][64 * BK];   // 8 KB
  __shared__ __align__(16) short sB3[2][64 * BK];   // 8 KB

  const int tid = threadIdx.x;
  const int w = tid >> 6;
  const int lane = tid & 63;
  const int lr = lane & 15;
  const int kq = lane >> 4;
  const int pq = kq ^ ((lr >> 1) & 3);
  const int wt = w >> 1;                    // token group: rows [wt*64, wt*64+64)
  const int wi = w & 1;                     // inter group: cols [wi*32, wi*32+32)
  const bool wactive = (wt * 64 < cnt - n0);

  // A staging: block-cooperative, 2 x 1KB segments per wave (16 segs = 256 rows)
  const short* gA[2];
#pragma unroll
  for (int j = 0; j < 2; ++j) {
    int seg = w * 2 + j;
    int q = seg * 64 + lane;
    int row = q >> 2;
    int qp = q & 3;
    int ql = qp ^ ((row >> 1) & 3);
    int trow = n0 + row; if (trow > cnt - 1) trow = cnt - 1;
    gA[j] = xg + (size_t)(off_e + trow) * D_DIM + ql * 8;
  }
  // B staging: all 512 threads; 0..255 -> w1, 256..511 -> w3; 8 f32 each
  const int bts = tid & 255;
  const int bwr = bts >> 2;                 // row 0..63
  const int bqp = bts & 3;
  const float* gB;
  {
    int ql = bqp ^ ((bwr >> 1) & 3);
    const float* wsel = (tid < 256) ? w1 : w3;
    gB = wsel + (size_t)e * I_DIM * D_DIM + (size_t)(m0 + bwr) * D_DIM + ql * 8;
  }

  f32x4 acc1[4][2], acc3[4][2];
#pragma unroll
  for (int mi = 0; mi < 4; ++mi)
#pragma unroll
    for (int ni = 0; ni < 2; ++ni) {
      acc1[mi][ni] = (f32x4){0.f, 0.f, 0.f, 0.f};
      acc3[mi][ni] = (f32x4){0.f, 0.f, 0.f, 0.f};
    }

  auto stageA = [&](int nb, int k0) {
#pragma unroll
    for (int j = 0; j < 2; ++j)
      gload_lds16(gA[j] + k0, &sA[nb][(w * 2 + j) * 512]);
  };
  auto loadB = [&](int k0, f32x4& ra, f32x4& rb) {
    const float* p = gB + k0;
    ra = *(const f32x4*)p;
    rb = *(const f32x4*)(p + 4);
  };
  auto writeB = [&](int nb, const f32x4& ra, const f32x4& rb) {
    bf16x8 o;
#pragma unroll
    for (int j = 0; j < 4; ++j) { o[j] = f2bf(ra[j]); o[4 + j] = f2bf(rb[j]); }
    short* dst = ((tid < 256) ? sB1[nb] : sB3[nb]) + bwr * BK + bqp * 8;
    *(bf16x8*)dst = o;
  };

  const int NSTEP = D_DIM / BK;   // 64
  {
    f32x4 ra, rb;
    stageA(0, 0);
    loadB(0, ra, rb);
    writeB(0, ra, rb);
    __syncthreads();
  }
  for (int t = 0; t < NSTEP; ++t) {
    const int nb = t & 1, pf = nb ^ 1;
    const bool pfv = (t + 1 < NSTEP);
    f32x4 ra, rb;
    if (pfv) {
      stageA(pf, (t + 1) * BK);
      loadB((t + 1) * BK, ra, rb);
    }
    if (wactive) {
      const short* Ab = sA[nb] + ((wt * 64 + lr) * BK + pq * 8);
      bf16x8 af[4];
#pragma unroll
      for (int mi = 0; mi < 4; ++mi)
        af[mi] = *(const bf16x8*)(Ab + mi * 16 * BK);
#pragma unroll
      for (int ni = 0; ni < 2; ++ni) {
        const int brow = wi * 32 + ni * 16 + lr;
        bf16x8 b1 = *(const bf16x8*)(sB1[nb] + brow * BK + pq * 8);
        bf16x8 b3 = *(const bf16x8*)(sB3[nb] + brow * BK + pq * 8);
#pragma unroll
        for (int mi = 0; mi < 4; ++mi) {
          acc1[mi][ni] = __builtin_amdgcn_mfma_f32_16x16x32_bf16(af[mi], b1, acc1[mi][ni], 0, 0, 0);
          acc3[mi][ni] = __builtin_amdgcn_mfma_f32_16x16x32_bf16(af[mi], b3, acc3[mi][ni], 0, 0, 0);
        }
      }
    }
    if (pfv) writeB(pf, ra, rb);
    __syncthreads();
  }

  if (wactive) {
#pragma unroll
    for (int mi = 0; mi < 4; ++mi)
#pragma unroll
      for (int ni = 0; ni < 2; ++ni)
#pragma unroll
        for (int j = 0; j < 4; ++j) {
          int row = wt * 64 + mi * 16 + kq * 4 + j;   // C/D: col=lane&15, row=(lane>>4)*4+j
          if (n0 + row < cnt) {
            int col = m0 + wi * 32 + ni * 16 + lr;
            float z1 = acc1[mi][ni][j];
            float z3 = acc3[mi][ni][j];
            float sv = z1 / (1.0f + __expf(-z1));
            h[(size_t)(off_e + n0 + row) * I_DIM + col] = f2bf(sv * z3);
          }
        }
  }
}

// ---------------- GEMM2: 256 tok x 64 d, 8 waves (64x32 each) ----------------
__global__ __launch_bounds__(512, 4)
void gemm2_out(const short* __restrict__ h, const float* __restrict__ w2,
               const int* __restrict__ off, const int* __restrict__ perm,
               float* __restrict__ out) {
  const int e = blockIdx.z;
  const int off_e = off[e];
  const int cnt = off[e + 1] - off_e;
  const int n0 = blockIdx.y * 256;
  if (n0 >= cnt) return;
  const int d0 = blockIdx.x * 64;

  __shared__ __align__(16) short sA[2][256 * BK];   // 32 KB
  __shared__ __align__(16) short sB[2][64 * BK];    // 8 KB

  const int tid = threadIdx.x;
  const int w = tid >> 6;
  const int lane = tid & 63;
  const int lr = lane & 15;
  const int kq = lane >> 4;
  const int pq = kq ^ ((lr >> 1) & 3);
  const int wt = w >> 1;
  const int wi = w & 1;
  const bool wactive = (wt * 64 < cnt - n0);

  const short* gA[2];
#pragma unroll
  for (int j = 0; j < 2; ++j) {
    int seg = w * 2 + j;
    int q = seg * 64 + lane;
    int row = q >> 2;
    int qp = q & 3;
    int ql = qp ^ ((row >> 1) & 3);
    int trow = n0 + row; if (trow > cnt - 1) trow = cnt - 1;
    gA[j] = h + (size_t)(off_e + trow) * I_DIM + ql * 8;
  }
  const bool bstage = (tid < 256);
  const int bwr = (tid & 255) >> 2;
  const int bqp = tid & 3;
  const float* gB;
  {
    int ql = bqp ^ ((bwr >> 1) & 3);
    gB = w2 + (size_t)e * D_DIM * I_DIM + (size_t)(d0 + bwr) * I_DIM + ql * 8;
  }

  f32x4 acc[4][2];
#pragma unroll
  for (int mi = 0; mi < 4; ++mi)
#pragma unroll
    for (int ni = 0; ni < 2; ++ni) acc[mi][ni] = (f32x4){0.f, 0.f, 0.f, 0.f};

  auto stageA = [&](int nb, int k0) {
#pragma unroll
    for (int j = 0; j < 2; ++j)
      gload_lds16(gA[j] + k0, &sA[nb][(w * 2 + j) * 512]);
  };
  auto loadB = [&](int k0, f32x4& ra, f32x4& rb) {
    if (bstage) {
      const float* p = gB + k0;
      ra = *(const f32x4*)p;
      rb = *(const f32x4*)(p + 4);
    }
  };
  auto writeB = [&](int nb, const f32x4& ra, const f32x4& rb) {
    if (bstage) {
      bf16x8 o;
#pragma unroll
      for (int j = 0; j < 4; ++j) { o[j] = f2bf(ra[j]); o[4 + j] = f2bf(rb[j]); }
      *(bf16x8*)(sB[nb] + bwr * BK + bqp * 8) = o;
    }
  };

  const int NSTEP = I_DIM / BK;   // 128
  {
    f32x4 ra, rb;
    stageA(0, 0);
    loadB(0, ra, rb);
    writeB(0, ra, rb);
    __syncthreads();
  }
  for (int t = 0; t < NSTEP; ++t) {
    const int nb = t & 1, pf = nb ^ 1;
    const bool pfv = (t + 1 < NSTEP);
    f32x4 ra, rb;
    if (pfv) {
      stageA(pf, (t + 1) * BK);
      loadB((t + 1) * BK, ra, rb);
    }
    if (wactive) {
      const short* Ab = sA[nb] + ((wt * 64 + lr) * BK + pq * 8);
      bf16x8 af[4];
#pragma unroll
      for (int mi = 0; mi < 4; ++mi)
        af[mi] = *(const bf16x8*)(Ab + mi * 16 * BK);
#pragma unroll
      for (int ni = 0; ni < 2; ++ni) {
        const int brow = wi * 32 + ni * 16 + lr;
        bf16x8 b = *(const bf16x8*)(sB[nb] + brow * BK + pq * 8);
#pragma unroll
        for (int mi = 0; mi < 4; ++mi)
          acc[mi][ni] = __builtin_amdgcn_mfma_f32_16x16x32_bf16(af[mi], b, acc[mi][ni], 0, 0, 0);
      }
    }
    if (pfv) writeB(pf, ra, rb);
    __syncthreads();
  }

  if (wactive) {
#pragma unroll
    for (int mi = 0; mi < 4; ++mi)
#pragma unroll
      for (int j = 0; j < 4; ++j) {
        int row = wt * 64 + mi * 16 + kq * 4 + j;
        if (n0 + row < cnt) {
          int oi = perm[off_e + n0 + row];
#pragma unroll
          for (int ni = 0; ni < 2; ++ni)
            out[(size_t)oi * D_DIM + d0 + wi * 32 + ni * 16 + lr] = acc[mi][ni][j];
        }
      }
  }
}

// ---------------- launch -----------------------------------------------------
extern "C" void kernel_launch(void* const* d_in, const int* in_sizes, int n_in,
                              void* d_out, int out_size, void* d_ws, size_t ws_size,
                              hipStream_t stream) {
  const float* x  = (const float*)d_in[0];
  const int* idx  = (const int*)d_in[1];
  const float* w1 = (const float*)d_in[2];
  const float* w2 = (const float*)d_in[3];
  const float* w3 = (const float*)d_in[4];
  float* out = (float*)d_out;

  int* off  = (int*)d_ws;
  int* perm = off + 16;
  short* xg = (short*)((char*)d_ws + 32768);
  short* h  = (short*)((char*)d_ws + 32768 + (size_t)16 * 1024 * 1024);

  route_kernel<<<1, 1024, 0, stream>>>(idx, off, perm);
  gather_x<<<TA, 256, 0, stream>>>(x, perm, xg);
  gemm1_w13<<<dim3(I_DIM / 64, TA / 256, E_EXP), 512, 0, stream>>>(xg, w1, w3, off, h);
  gemm2_out<<<dim3(D_DIM / 64, TA / 256, E_EXP), 512, 0, stream>>>(h, w2, off, perm, out);
}